// Round 12
// baseline (233.714 us; speedup 1.0000x reference)
//
#include <hip/hip_runtime.h>
#include <hip/hip_bf16.h>
#include <cstdint>

#define THREADS 256

typedef __attribute__((ext_vector_type(8))) short bf16x8;
typedef __attribute__((ext_vector_type(4))) float f32x4;

__device__ __forceinline__ void load_lds16(const void* g, void* l) {
    __builtin_amdgcn_global_load_lds(
        (const __attribute__((address_space(1))) unsigned int*)g,
        (__attribute__((address_space(3))) unsigned int*)l, 16, 0, 0);
}

__device__ __forceinline__ unsigned short f2bf(float x) {
    __hip_bfloat16 hb = __float2bfloat16(x);
    return *(unsigned short*)&hb;
}

// ---------------------------------------------------------------------------
// Fused fp32 -> bf16 cast of the six GEMM inputs. (wk,wv land contiguously)
// ---------------------------------------------------------------------------
__global__ __launch_bounds__(THREADS)
void cast_inputs(const float* __restrict__ xq, const float* __restrict__ xkv,
                 const float* __restrict__ wq, const float* __restrict__ wk,
                 const float* __restrict__ wv, const float* __restrict__ wo,
                 unsigned short* __restrict__ oq, unsigned short* __restrict__ okv,
                 unsigned short* __restrict__ owq, unsigned short* __restrict__ owk,
                 unsigned short* __restrict__ owv, unsigned short* __restrict__ owo) {
    const unsigned n0 = 524288, n1 = 1572864, n2 = 262144, n3 = 196608, n4 = 196608;
    unsigned i = blockIdx.x * THREADS + threadIdx.x;  // < 3014656
    const float* src; unsigned short* dst; unsigned off;
    if (i < n0)                    { src = xq;  dst = oq;  off = i; }
    else if (i < n0+n1)            { src = xkv; dst = okv; off = i - n0; }
    else if (i < n0+n1+n2)         { src = wq;  dst = owq; off = i - n0 - n1; }
    else if (i < n0+n1+n2+n3)      { src = wk;  dst = owk; off = i - n0 - n1 - n2; }
    else if (i < n0+n1+n2+n3+n4)   { src = wv;  dst = owv; off = i - n0 - n1 - n2 - n3; }
    else                           { src = wo;  dst = owo; off = i - n0 - n1 - n2 - n3 - n4; }
    float4 v = *(const float4*)(src + (size_t)off * 4);
    ushort4 o;
    o.x = f2bf(v.x); o.y = f2bf(v.y); o.z = f2bf(v.z); o.w = f2bf(v.w);
    *(ushort4*)(dst + (size_t)off * 4) = o;
}

// ---------------------------------------------------------------------------
// 64x64-tile bf16 MFMA GEMM (small Q / Wo projections). 512 blocks @ 2048x1024.
// ---------------------------------------------------------------------------
template <bool OUTF32>
__global__ __launch_bounds__(THREADS)
void gemm_bf16_nt64(const unsigned short* __restrict__ A, const unsigned short* __restrict__ W,
                    void* __restrict__ Cout, int M, int N, int Kd) {
    __shared__ __align__(16) unsigned short As[64 * 64];
    __shared__ __align__(16) unsigned short Bs[64 * 64];

    const int t    = threadIdx.x;
    const int w    = t >> 6;
    const int lane = t & 63;
    const int l15  = lane & 15;
    const int quad = lane >> 4;
    const int wm   = w & 1;
    const int wn   = w >> 1;
    const int bM = blockIdx.y * 64;
    const int bN = blockIdx.x * 64;

    const int srow = t >> 3;
    const int scol = ((t & 7) ^ ((t >> 3) & 7)) << 3;
    const unsigned short* ga = A + (size_t)(bM + srow) * Kd + scol;
    const unsigned short* gb = W + (size_t)(bN + srow) * Kd + scol;
    const int lbase = w * 512;

    int aoff[2][2], boff[2][2];
#pragma unroll
    for (int kk = 0; kk < 2; ++kk)
#pragma unroll
        for (int mt = 0; mt < 2; ++mt) {
            aoff[kk][mt] = (wm * 32 + mt * 16 + l15) * 64 + (((kk * 4 + quad) ^ (l15 & 7)) << 3);
            boff[kk][mt] = (wn * 32 + mt * 16 + l15) * 64 + (((kk * 4 + quad) ^ (l15 & 7)) << 3);
        }

    f32x4 acc[2][2];
#pragma unroll
    for (int mt = 0; mt < 2; ++mt)
#pragma unroll
        for (int nt = 0; nt < 2; ++nt)
#pragma unroll
            for (int r = 0; r < 4; ++r) acc[mt][nt][r] = 0.f;

    for (int k0 = 0; k0 < Kd; k0 += 64) {
        __syncthreads();
#pragma unroll
        for (int it = 0; it < 2; ++it) {
            load_lds16(ga + (size_t)it * 32 * Kd + k0, &As[lbase + it * 2048]);
            load_lds16(gb + (size_t)it * 32 * Kd + k0, &Bs[lbase + it * 2048]);
        }
        __syncthreads();

#pragma unroll
        for (int kk = 0; kk < 2; ++kk) {
            bf16x8 af[2], bf[2];
#pragma unroll
            for (int mt = 0; mt < 2; ++mt) af[mt] = *(const bf16x8*)&As[aoff[kk][mt]];
#pragma unroll
            for (int nt = 0; nt < 2; ++nt) bf[nt] = *(const bf16x8*)&Bs[boff[kk][nt]];
#pragma unroll
            for (int mt = 0; mt < 2; ++mt)
#pragma unroll
                for (int nt = 0; nt < 2; ++nt)
                    acc[mt][nt] = __builtin_amdgcn_mfma_f32_16x16x32_bf16(af[mt], bf[nt], acc[mt][nt], 0, 0, 0);
        }
    }

#pragma unroll
    for (int mt = 0; mt < 2; ++mt)
#pragma unroll
        for (int r = 0; r < 4; ++r) {
            int row = bM + wm * 32 + mt * 16 + quad * 4 + r;
            int col = bN + wn * 32 + l15;
            if (OUTF32) {
                float* cp = (float*)Cout + (size_t)row * N + col;
#pragma unroll
                for (int nt = 0; nt < 2; ++nt) cp[nt * 16] = acc[mt][nt][r];
            } else {
                unsigned short* cp = (unsigned short*)Cout + (size_t)row * N + col;
#pragma unroll
                for (int nt = 0; nt < 2; ++nt) cp[nt * 16] = f2bf(acc[mt][nt][r]);
            }
        }
}

// ---------------------------------------------------------------------------
// Fused K+V projection GEMM with PERMUTED-KV epilogue (verified r9).
// Shared kv-bijection j = (c>>6)*256 + (s&255):
//   K -> Kn[bh][j][d], V -> Vt[bh][d][j].
// ---------------------------------------------------------------------------
__global__ __launch_bounds__(THREADS)
void gemm_bf16_kvt(const unsigned short* __restrict__ A, const unsigned short* __restrict__ W,
                   unsigned short* __restrict__ Kn, unsigned short* __restrict__ Vt,
                   int M, int Kd) {
    __shared__ __align__(16) unsigned short As[128 * 64];
    __shared__ __align__(16) unsigned short Bs[128 * 64];

    const int t    = threadIdx.x;
    const int w    = t >> 6;
    const int lane = t & 63;
    const int l15  = lane & 15;
    const int quad = lane >> 4;
    const int wm   = w & 1;
    const int wn   = w >> 1;
    const int bM = blockIdx.y * 128;
    const int bN = blockIdx.x * 128;

    const int srow = t >> 3;
    const int scol = ((t & 7) ^ ((t >> 4) & 7)) << 3;
    const unsigned short* ga = A + (size_t)(bM + srow) * Kd + scol;
    const unsigned short* gb = W + (size_t)(bN + srow) * Kd + scol;
    const int lbase = w * 512;

    const int xr = (l15 >> 1) & 7;
    int aoff[2][4], boff[2][4];
#pragma unroll
    for (int kk = 0; kk < 2; ++kk)
#pragma unroll
        for (int mt = 0; mt < 4; ++mt) {
            aoff[kk][mt] = (wm * 64 + mt * 16 + l15) * 64 + (((kk * 4 + quad) ^ xr) << 3);
            boff[kk][mt] = (wn * 64 + mt * 16 + l15) * 64 + (((kk * 4 + quad) ^ xr) << 3);
        }

    f32x4 acc[4][4];
#pragma unroll
    for (int mt = 0; mt < 4; ++mt)
#pragma unroll
        for (int nt = 0; nt < 4; ++nt)
#pragma unroll
            for (int r = 0; r < 4; ++r) acc[mt][nt][r] = 0.f;

    for (int k0 = 0; k0 < Kd; k0 += 64) {
        __syncthreads();
#pragma unroll
        for (int it = 0; it < 4; ++it) {
            load_lds16(ga + (size_t)it * 32 * Kd + k0, &As[lbase + it * 2048]);
            load_lds16(gb + (size_t)it * 32 * Kd + k0, &Bs[lbase + it * 2048]);
        }
        __syncthreads();

#pragma unroll
        for (int kk = 0; kk < 2; ++kk) {
            bf16x8 af[4], bf[4];
#pragma unroll
            for (int mt = 0; mt < 4; ++mt) af[mt] = *(const bf16x8*)&As[aoff[kk][mt]];
#pragma unroll
            for (int nt = 0; nt < 4; ++nt) bf[nt] = *(const bf16x8*)&Bs[boff[kk][nt]];
#pragma unroll
            for (int mt = 0; mt < 4; ++mt)
#pragma unroll
                for (int nt = 0; nt < 4; ++nt)
                    acc[mt][nt] = __builtin_amdgcn_mfma_f32_16x16x32_bf16(af[mt], bf[nt], acc[mt][nt], 0, 0, 0);
        }
    }

    const int rbase = bM + wm * 64;
    const int b  = rbase >> 12;
    const int h  = (rbase & 4095) >> 8;
    if (bN < 1024) {
        const int G = (bN + wn * 64) >> 6;
        unsigned short* kp = Kn + (size_t)(b * 16 + h) * 262144 + (size_t)G * 256 * 64 + l15;
#pragma unroll
        for (int mt = 0; mt < 4; ++mt)
#pragma unroll
            for (int r = 0; r < 4; ++r) {
                int u = (rbase & 255) + mt * 16 + quad * 4 + r;
                unsigned short* cp = kp + (size_t)u * 64;
#pragma unroll
                for (int nt = 0; nt < 4; ++nt) cp[nt * 16] = f2bf(acc[mt][nt][r]);
            }
    } else {
        const int Gv = (bN - 1024 + wn * 64) >> 6;
        unsigned short* vp = Vt + (size_t)(b * 16 + h) * 262144 + (size_t)Gv * 256;
#pragma unroll
        for (int nt = 0; nt < 4; ++nt) {
            int d = nt * 16 + l15;
#pragma unroll
            for (int mt = 0; mt < 4; ++mt) {
                int u = (rbase & 255) + mt * 16 + quad * 4;
                ushort4 pk;
                pk.x = f2bf(acc[mt][nt][0]);
                pk.y = f2bf(acc[mt][nt][1]);
                pk.z = f2bf(acc[mt][nt][2]);
                pk.w = f2bf(acc[mt][nt][3]);
                *(ushort4*)(vp + (size_t)d * 4096 + u) = pk;
            }
        }
    }
}

// ---------------------------------------------------------------------------
// Flash attention v7: r11 structure (64q x 32kv per wave, S^T trick, __expf)
// + kv-split 2 for occupancy:
//  - grid 1024: each block handles kv [half*2048, +2048) of one (b,h,q-block),
//    writes UNNORMALIZED f32 O-partial + l-sums (max-free softmax partials
//    add linearly — combine merges; r6-verified math).
//  - dynamic LDS trimmed to 53248 B (Lw overlays the dead Ps tail) -> 3
//    blocks/CU; grid 1024 now actually fills them (was 2/CU grid-limited,
//    pipes serialized: DS 21 + VALU 23 + MFMA 13 ≈ 67 µs wall).
//  - XCD swizzle: bid&7 = hh&7 keeps all 32 blocks of one (b,h) on one XCD.
// ---------------------------------------------------------------------------
__global__ __launch_bounds__(THREADS, 3)
void attn_mfma7(const unsigned short* __restrict__ Q, const unsigned short* __restrict__ K,
                const unsigned short* __restrict__ Vt, float* __restrict__ Op,
                float* __restrict__ Lp) {
    extern __shared__ __align__(16) unsigned short sm[];
    unsigned short* Ks = sm;              // [128kv][64d] swizzled, 8192 shorts
    unsigned short* Vs = sm + 8192;       // [64d][128kv] swizzled, 8192 shorts
    unsigned short* Ps = sm + 16384;      // 4 waves x [64q][40], 10240 shorts
    float* OS = (float*)sm;               // epilogue: 3 x [64d][68q] f32 (52224 B)
    float* Lw = (float*)(sm + 26112);     // 256 f32 at bytes 52224..53248 (Ps tail, epilogue-only)

    const int bid  = blockIdx.x;          // 0..1023
    const int slot = bid >> 3;            // 0..127
    const int hh   = (bid & 7) + 8 * (slot >> 5);   // 0..31, XCD = hh&7
    const int rem  = slot & 31;
    const int qq   = rem >> 1;            // 0..15
    const int half = rem & 1;             // kv half
    const int q0 = qq * 64;
    const int h  = hh & 15;
    const int b  = hh >> 4;

    const int t    = threadIdx.x;
    const int w    = t >> 6;              // kv-quarter owner (within this half)
    const int lane = t & 63;
    const int l15  = lane & 15;
    const int quad = lane >> 4;

    const unsigned short* Qh = Q + (size_t)b * 1048576 + (size_t)h * 65536 + (size_t)q0 * 64;
    const unsigned short* Kh = K + (size_t)b * 4194304 + (size_t)h * 262144;
    const unsigned short* Vh = Vt + (size_t)(b * 16 + h) * 262144;

    bf16x8 Qb[4][2];
#pragma unroll
    for (int qt = 0; qt < 4; ++qt)
#pragma unroll
        for (int kk = 0; kk < 2; ++kk)
            Qb[qt][kk] = *(const bf16x8*)(Qh + (size_t)(qt * 16 + l15) * 64 + kk * 32 + quad * 8);

    const unsigned short* gK = Kh + (size_t)(t >> 3) * 64 + (((t & 7) ^ ((t >> 3) & 7)) << 3);
    const unsigned short* gV = Vh + (size_t)(t >> 4) * 4096 + (((t & 15) ^ ((t >> 4) & 7)) << 3);
    const int lb = w * 512;

    int koff[2][2];
#pragma unroll
    for (int kvt = 0; kvt < 2; ++kvt)
#pragma unroll
        for (int kk = 0; kk < 2; ++kk)
            koff[kvt][kk] = (w * 32 + kvt * 16 + l15) * 64 + (((kk * 4 + quad) ^ (l15 & 7)) << 3);
    int voff[4];
#pragma unroll
    for (int dt = 0; dt < 4; ++dt)
        voff[dt] = (dt * 16 + l15) * 128 + (((w * 4 + quad) ^ (l15 & 7)) << 3);

    const int pw  = w * 2560;
    const int pq  = pw + l15 * 40;

    f32x4 Oacc[4][4];
#pragma unroll
    for (int qt = 0; qt < 4; ++qt)
#pragma unroll
        for (int dt = 0; dt < 4; ++dt)
#pragma unroll
            for (int r = 0; r < 4; ++r) Oacc[qt][dt][r] = 0.f;
    float lsum[4] = {0.f, 0.f, 0.f, 0.f};

    const float scale = 1.0f / 64.0f;

    for (int kc = half * 16; kc < half * 16 + 16; ++kc) {
        __syncthreads();   // (A) prior frag reads done
#pragma unroll
        for (int it = 0; it < 4; ++it)
            load_lds16(gK + (size_t)kc * 8192 + it * 2048, &Ks[lb + it * 2048]);
#pragma unroll
        for (int it = 0; it < 4; ++it)
            load_lds16(gV + (size_t)kc * 128 + (size_t)it * 65536, &Vs[lb + it * 2048]);
        __syncthreads();   // (B) tiles visible

        // ---- S^T tiles (16kv x 16q), __expf, b64 P store ----
#pragma unroll
        for (int kvt = 0; kvt < 2; ++kvt) {
            bf16x8 ka = *(const bf16x8*)&Ks[koff[kvt][0]];
            bf16x8 kb = *(const bf16x8*)&Ks[koff[kvt][1]];
#pragma unroll
            for (int qt = 0; qt < 4; ++qt) {
                f32x4 S = {0.f, 0.f, 0.f, 0.f};
                S = __builtin_amdgcn_mfma_f32_16x16x32_bf16(ka, Qb[qt][0], S, 0, 0, 0);
                S = __builtin_amdgcn_mfma_f32_16x16x32_bf16(kb, Qb[qt][1], S, 0, 0, 0);
                float p0 = __expf(S[0] * scale);
                float p1 = __expf(S[1] * scale);
                float p2 = __expf(S[2] * scale);
                float p3 = __expf(S[3] * scale);
                lsum[qt] += (p0 + p1) + (p2 + p3);
                ushort4 pk4;
                pk4.x = f2bf(p0); pk4.y = f2bf(p1); pk4.z = f2bf(p2); pk4.w = f2bf(p3);
                *(ushort4*)&Ps[pq + qt * 640 + kvt * 16 + quad * 4] = pk4;
            }
        }
        asm volatile("s_waitcnt lgkmcnt(0)" ::: "memory");  // wave-private P

        // ---- O += P @ V over this wave's 32 kv ----
        bf16x8 Vf[4];
#pragma unroll
        for (int dt = 0; dt < 4; ++dt) Vf[dt] = *(const bf16x8*)&Vs[voff[dt]];
#pragma unroll
        for (int qt = 0; qt < 4; ++qt) {
            bf16x8 Pa = *(const bf16x8*)&Ps[pq + qt * 640 + quad * 8];
#pragma unroll
            for (int dt = 0; dt < 4; ++dt)
                Oacc[qt][dt] = __builtin_amdgcn_mfma_f32_16x16x32_bf16(Pa, Vf[dt], Oacc[qt][dt], 0, 0, 0);
        }
    }

    // ---- epilogue: merge 4 kv-quarter partials, write f32 partial + l ----
#pragma unroll
    for (int qt = 0; qt < 4; ++qt) {
        float v = lsum[qt];
        v += __shfl_xor(v, 16);
        v += __shfl_xor(v, 32);
        lsum[qt] = v;
    }
    __syncthreads();   // (1) all frag reads of Ks/Vs/Ps done
    if (lane < 16) {
#pragma unroll
        for (int qt = 0; qt < 4; ++qt)
            Lw[w * 64 + qt * 16 + lane] = lsum[qt];
    }
    if (w > 0) {
        float* myOS = OS + (w - 1) * 4352;   // [64d][stride 68] f32
#pragma unroll
        for (int qt = 0; qt < 4; ++qt)
#pragma unroll
            for (int dt = 0; dt < 4; ++dt)
                *(f32x4*)&myOS[(dt * 16 + l15) * 68 + qt * 16 + quad * 4] = Oacc[qt][dt];
    }
    __syncthreads();   // (2) partials + Lw visible
    if (w == 0) {
#pragma unroll
        for (int qt = 0; qt < 4; ++qt) {
            f32x4 lv = *(const f32x4*)&Lw[qt * 16 + quad * 4];
            lv += *(const f32x4*)&Lw[64 + qt * 16 + quad * 4];
            lv += *(const f32x4*)&Lw[128 + qt * 16 + quad * 4];
            lv += *(const f32x4*)&Lw[192 + qt * 16 + quad * 4];
            if (l15 == 0) {
#pragma unroll
                for (int r = 0; r < 4; ++r) {
                    int q = qt * 16 + quad * 4 + r;
                    Lp[(size_t)half * 32768 + ((size_t)b * 1024 + q0 + q) * 16 + h] = lv[r];
                }
            }
#pragma unroll
            for (int dt = 0; dt < 4; ++dt) {
                f32x4 o = Oacc[qt][dt];
                int os = (dt * 16 + l15) * 68 + qt * 16 + quad * 4;
                o += *(const f32x4*)&OS[os];
                o += *(const f32x4*)&OS[4352 + os];
                o += *(const f32x4*)&OS[8704 + os];
#pragma unroll
                for (int r = 0; r < 4; ++r) {
                    int q = qt * 16 + quad * 4 + r;
                    Op[(size_t)half * 2097152 + ((size_t)b * 1024 + q0 + q) * 1024
                       + (h << 6) + dt * 16 + l15] = o[r];
                }
            }
        }
    }
}

// ---------------------------------------------------------------------------
// Combine the two kv-half partials: AO = bf16( (O0+O1) / (l0+l1) ).  (r6 math)
// ---------------------------------------------------------------------------
__global__ __launch_bounds__(THREADS)
void combine_o(const float* __restrict__ Op, const float* __restrict__ Lp,
               unsigned short* __restrict__ AO) {
    unsigned i = blockIdx.x * THREADS + threadIdx.x;   // < 524288
    unsigned flat = i * 4;
    unsigned bq = flat >> 10;
    unsigned h  = (flat & 1023) >> 6;
    float4 o0 = *(const float4*)(Op + flat);
    float4 o1 = *(const float4*)(Op + 2097152 + flat);
    float inv = 1.0f / (Lp[bq * 16 + h] + Lp[32768 + bq * 16 + h]);
    ushort4 o;
    o.x = f2bf((o0.x + o1.x) * inv);
    o.y = f2bf((o0.y + o1.y) * inv);
    o.z = f2bf((o0.z + o1.z) * inv);
    o.w = f2bf((o0.w + o1.w) * inv);
    *(ushort4*)(AO + flat) = o;
}

// ---------------------------------------------------------------------------
extern "C" void kernel_launch(void* const* d_in, const int* in_sizes, int n_in,
                              void* d_out, int out_size, void* d_ws, size_t ws_size,
                              hipStream_t stream) {
    const float* x_q  = (const float*)d_in[0];  // (2,1024,1024)
    const float* x_kv = (const float*)d_in[1];  // (2,4096,768)
    const float* Wq   = (const float*)d_in[2];
    const float* Wk   = (const float*)d_in[3];
    const float* Wv   = (const float*)d_in[4];
    const float* Wo   = (const float*)d_in[5];
    float* out = (float*)d_out;

    // ws (shorts). Op (f32, 16 MB) overlays xq_bf+xkv_bf (dead after the
    // projections). Lp in the free region after AOb.
    unsigned short* base   = (unsigned short*)d_ws;
    unsigned short* xq_bf  = base;                  // 2097152
    unsigned short* xkv_bf = base + 2097152;        // 6291456
    unsigned short* wq_bf  = base + 8388608;        // 1048576
    unsigned short* wk_bf  = base + 9437184;        //  786432  \ contiguous
    unsigned short* wv_bf  = base + 10223616;       //  786432  / [2048][768]
    unsigned short* wo_bf  = base + 11010048;       // 1048576
    unsigned short* Qw     = base + 12058624;       // 2097152
    unsigned short* Kw     = base + 14155776;       // 8388608
    unsigned short* AOb    = base + 22544384;       // 2097152
    float*          Lp     = (float*)(base + 24641536); // 65536 f32
    unsigned short* Vtw    = base + 30932992;       // 8388608
    float*          Opf    = (float*)d_ws;          // 4194304 f32 (overlays casts)

    dim3 blk(THREADS);
    cast_inputs<<<dim3(11776), blk, 0, stream>>>(x_q, x_kv, Wq, Wk, Wv, Wo,
                                                 xq_bf, xkv_bf, wq_bf, wk_bf, wv_bf, wo_bf);
    gemm_bf16_nt64<false><<<dim3(16, 32), blk, 0, stream>>>(xq_bf, wq_bf, (void*)Qw, 2048, 1024, 1024);
    gemm_bf16_kvt<<<dim3(16, 64), blk, 0, stream>>>(xkv_bf, wk_bf, Kw, Vtw, 8192, 768);
    attn_mfma7<<<dim3(1024), blk, 53248, stream>>>(Qw, Kw, Vtw, Opf, Lp);
    combine_o<<<dim3(2048), blk, 0, stream>>>(Opf, Lp, AOb);
    gemm_bf16_nt64<true><<<dim3(16, 32), blk, 0, stream>>>(AOb, wo_bf, (void*)out, 2048, 1024, 1024);
}

// Round 13
// 209.222 us; speedup vs baseline: 1.1171x; 1.1171x over previous
//
#include <hip/hip_runtime.h>
#include <hip/hip_bf16.h>
#include <cstdint>

#define THREADS 256

typedef __attribute__((ext_vector_type(8))) short bf16x8;
typedef __attribute__((ext_vector_type(4))) float f32x4;

__device__ __forceinline__ void load_lds16(const void* g, void* l) {
    __builtin_amdgcn_global_load_lds(
        (const __attribute__((address_space(1))) unsigned int*)g,
        (__attribute__((address_space(3))) unsigned int*)l, 16, 0, 0);
}

__device__ __forceinline__ unsigned short f2bf(float x) {
    __hip_bfloat16 hb = __float2bfloat16(x);
    return *(unsigned short*)&hb;
}

// ---------------------------------------------------------------------------
// Fused fp32 -> bf16 cast of the six GEMM inputs. (wk,wv land contiguously)
// ---------------------------------------------------------------------------
__global__ __launch_bounds__(THREADS)
void cast_inputs(const float* __restrict__ xq, const float* __restrict__ xkv,
                 const float* __restrict__ wq, const float* __restrict__ wk,
                 const float* __restrict__ wv, const float* __restrict__ wo,
                 unsigned short* __restrict__ oq, unsigned short* __restrict__ okv,
                 unsigned short* __restrict__ owq, unsigned short* __restrict__ owk,
                 unsigned short* __restrict__ owv, unsigned short* __restrict__ owo) {
    const unsigned n0 = 524288, n1 = 1572864, n2 = 262144, n3 = 196608, n4 = 196608;
    unsigned i = blockIdx.x * THREADS + threadIdx.x;  // < 3014656
    const float* src; unsigned short* dst; unsigned off;
    if (i < n0)                    { src = xq;  dst = oq;  off = i; }
    else if (i < n0+n1)            { src = xkv; dst = okv; off = i - n0; }
    else if (i < n0+n1+n2)         { src = wq;  dst = owq; off = i - n0 - n1; }
    else if (i < n0+n1+n2+n3)      { src = wk;  dst = owk; off = i - n0 - n1 - n2; }
    else if (i < n0+n1+n2+n3+n4)   { src = wv;  dst = owv; off = i - n0 - n1 - n2 - n3; }
    else                           { src = wo;  dst = owo; off = i - n0 - n1 - n2 - n3 - n4; }
    float4 v = *(const float4*)(src + (size_t)off * 4);
    ushort4 o;
    o.x = f2bf(v.x); o.y = f2bf(v.y); o.z = f2bf(v.z); o.w = f2bf(v.w);
    *(ushort4*)(dst + (size_t)off * 4) = o;
}

// ---------------------------------------------------------------------------
// MERGED projection dispatch (grid 1536):
//  blocks [0,1024):   KV GEMM with permuted-KV epilogue (verified r9)
//  blocks [1024,1536): Q GEMM, 64x64 tiles (verified r8/r9 nt64 path)
// Independent outputs, both feed attention -> safe to co-schedule; removes a
// launch gap and lets Q blocks fill CUs the KV GEMM leaves idle.
// ---------------------------------------------------------------------------
__global__ __launch_bounds__(THREADS)
void gemm_proj(const unsigned short* __restrict__ xkv, const unsigned short* __restrict__ wkv,
               unsigned short* __restrict__ Kn, unsigned short* __restrict__ Vt,
               const unsigned short* __restrict__ xq, const unsigned short* __restrict__ wq,
               unsigned short* __restrict__ Qout) {
    __shared__ __align__(16) unsigned short As[128 * 64];
    __shared__ __align__(16) unsigned short Bs[128 * 64];

    const int t    = threadIdx.x;
    const int w    = t >> 6;
    const int lane = t & 63;
    const int l15  = lane & 15;
    const int quad = lane >> 4;
    const int wm   = w & 1;
    const int wn   = w >> 1;

    if (blockIdx.x < 1024) {
        // ---------------- KV path: 128x128 tile, Kd=768 ----------------
        const int bN = (blockIdx.x & 15) * 128;
        const int bM = (blockIdx.x >> 4) * 128;
        const int Kd = 768;

        const int srow = t >> 3;
        const int scol = ((t & 7) ^ ((t >> 4) & 7)) << 3;
        const unsigned short* ga = xkv + (size_t)(bM + srow) * Kd + scol;
        const unsigned short* gb = wkv + (size_t)(bN + srow) * Kd + scol;
        const int lbase = w * 512;

        const int xr = (l15 >> 1) & 7;
        int aoff[2][4], boff[2][4];
#pragma unroll
        for (int kk = 0; kk < 2; ++kk)
#pragma unroll
            for (int mt = 0; mt < 4; ++mt) {
                aoff[kk][mt] = (wm * 64 + mt * 16 + l15) * 64 + (((kk * 4 + quad) ^ xr) << 3);
                boff[kk][mt] = (wn * 64 + mt * 16 + l15) * 64 + (((kk * 4 + quad) ^ xr) << 3);
            }

        f32x4 acc[4][4];
#pragma unroll
        for (int mt = 0; mt < 4; ++mt)
#pragma unroll
            for (int nt = 0; nt < 4; ++nt)
#pragma unroll
                for (int r = 0; r < 4; ++r) acc[mt][nt][r] = 0.f;

        for (int k0 = 0; k0 < Kd; k0 += 64) {
            __syncthreads();
#pragma unroll
            for (int it = 0; it < 4; ++it) {
                load_lds16(ga + (size_t)it * 32 * Kd + k0, &As[lbase + it * 2048]);
                load_lds16(gb + (size_t)it * 32 * Kd + k0, &Bs[lbase + it * 2048]);
            }
            __syncthreads();

#pragma unroll
            for (int kk = 0; kk < 2; ++kk) {
                bf16x8 af[4], bf[4];
#pragma unroll
                for (int mt = 0; mt < 4; ++mt) af[mt] = *(const bf16x8*)&As[aoff[kk][mt]];
#pragma unroll
                for (int nt = 0; nt < 4; ++nt) bf[nt] = *(const bf16x8*)&Bs[boff[kk][nt]];
#pragma unroll
                for (int mt = 0; mt < 4; ++mt)
#pragma unroll
                    for (int nt = 0; nt < 4; ++nt)
                        acc[mt][nt] = __builtin_amdgcn_mfma_f32_16x16x32_bf16(af[mt], bf[nt], acc[mt][nt], 0, 0, 0);
            }
        }

        const int rbase = bM + wm * 64;
        const int b  = rbase >> 12;
        const int h  = (rbase & 4095) >> 8;
        if (bN < 1024) {
            const int G = (bN + wn * 64) >> 6;
            unsigned short* kp = Kn + (size_t)(b * 16 + h) * 262144 + (size_t)G * 256 * 64 + l15;
#pragma unroll
            for (int mt = 0; mt < 4; ++mt)
#pragma unroll
                for (int r = 0; r < 4; ++r) {
                    int u = (rbase & 255) + mt * 16 + quad * 4 + r;
                    unsigned short* cp = kp + (size_t)u * 64;
#pragma unroll
                    for (int nt = 0; nt < 4; ++nt) cp[nt * 16] = f2bf(acc[mt][nt][r]);
                }
        } else {
            const int Gv = (bN - 1024 + wn * 64) >> 6;
            unsigned short* vp = Vt + (size_t)(b * 16 + h) * 262144 + (size_t)Gv * 256;
#pragma unroll
            for (int nt = 0; nt < 4; ++nt) {
                int d = nt * 16 + l15;
#pragma unroll
                for (int mt = 0; mt < 4; ++mt) {
                    int u = (rbase & 255) + mt * 16 + quad * 4;
                    ushort4 pk;
                    pk.x = f2bf(acc[mt][nt][0]);
                    pk.y = f2bf(acc[mt][nt][1]);
                    pk.z = f2bf(acc[mt][nt][2]);
                    pk.w = f2bf(acc[mt][nt][3]);
                    *(ushort4*)(vp + (size_t)d * 4096 + u) = pk;
                }
            }
        }
    } else {
        // ---------------- Q path: 64x64 tile, Kd=1024, N=1024 ----------------
        const int id = blockIdx.x - 1024;           // 0..511
        const int bN = (id & 15) * 64;
        const int bM = (id >> 4) * 64;
        const int Kd = 1024, N = 1024;

        const int srow = t >> 3;                    // 0..31
        const int scol = ((t & 7) ^ ((t >> 3) & 7)) << 3;
        const unsigned short* ga = xq + (size_t)(bM + srow) * Kd + scol;
        const unsigned short* gb = wq + (size_t)(bN + srow) * Kd + scol;
        const int lbase = w * 512;

        int aoff[2][2], boff[2][2];
#pragma unroll
        for (int kk = 0; kk < 2; ++kk)
#pragma unroll
            for (int mt = 0; mt < 2; ++mt) {
                aoff[kk][mt] = (wm * 32 + mt * 16 + l15) * 64 + (((kk * 4 + quad) ^ (l15 & 7)) << 3);
                boff[kk][mt] = (wn * 32 + mt * 16 + l15) * 64 + (((kk * 4 + quad) ^ (l15 & 7)) << 3);
            }

        f32x4 acc[2][2];
#pragma unroll
        for (int mt = 0; mt < 2; ++mt)
#pragma unroll
            for (int nt = 0; nt < 2; ++nt)
#pragma unroll
                for (int r = 0; r < 4; ++r) acc[mt][nt][r] = 0.f;

        for (int k0 = 0; k0 < Kd; k0 += 64) {
            __syncthreads();
#pragma unroll
            for (int it = 0; it < 2; ++it) {
                load_lds16(ga + (size_t)it * 32 * Kd + k0, &As[lbase + it * 2048]);
                load_lds16(gb + (size_t)it * 32 * Kd + k0, &Bs[lbase + it * 2048]);
            }
            __syncthreads();

#pragma unroll
            for (int kk = 0; kk < 2; ++kk) {
                bf16x8 af[2], bf[2];
#pragma unroll
                for (int mt = 0; mt < 2; ++mt) af[mt] = *(const bf16x8*)&As[aoff[kk][mt]];
#pragma unroll
                for (int nt = 0; nt < 2; ++nt) bf[nt] = *(const bf16x8*)&Bs[boff[kk][nt]];
#pragma unroll
                for (int mt = 0; mt < 2; ++mt)
#pragma unroll
                    for (int nt = 0; nt < 2; ++nt)
                        acc[mt][nt] = __builtin_amdgcn_mfma_f32_16x16x32_bf16(af[mt], bf[nt], acc[mt][nt], 0, 0, 0);
            }
        }

#pragma unroll
        for (int mt = 0; mt < 2; ++mt)
#pragma unroll
            for (int r = 0; r < 4; ++r) {
                int row = bM + wm * 32 + mt * 16 + quad * 4 + r;
                int col = bN + wn * 32 + l15;
                unsigned short* cp = Qout + (size_t)row * N + col;
#pragma unroll
                for (int nt = 0; nt < 2; ++nt) cp[nt * 16] = f2bf(acc[mt][nt][r]);
            }
    }
}

// ---------------------------------------------------------------------------
// 64x64-tile bf16 MFMA GEMM (Wo projection). 512 blocks @ 2048x1024.
// ---------------------------------------------------------------------------
template <bool OUTF32>
__global__ __launch_bounds__(THREADS)
void gemm_bf16_nt64(const unsigned short* __restrict__ A, const unsigned short* __restrict__ W,
                    void* __restrict__ Cout, int M, int N, int Kd) {
    __shared__ __align__(16) unsigned short As[64 * 64];
    __shared__ __align__(16) unsigned short Bs[64 * 64];

    const int t    = threadIdx.x;
    const int w    = t >> 6;
    const int lane = t & 63;
    const int l15  = lane & 15;
    const int quad = lane >> 4;
    const int wm   = w & 1;
    const int wn   = w >> 1;
    const int bM = blockIdx.y * 64;
    const int bN = blockIdx.x * 64;

    const int srow = t >> 3;
    const int scol = ((t & 7) ^ ((t >> 3) & 7)) << 3;
    const unsigned short* ga = A + (size_t)(bM + srow) * Kd + scol;
    const unsigned short* gb = W + (size_t)(bN + srow) * Kd + scol;
    const int lbase = w * 512;

    int aoff[2][2], boff[2][2];
#pragma unroll
    for (int kk = 0; kk < 2; ++kk)
#pragma unroll
        for (int mt = 0; mt < 2; ++mt) {
            aoff[kk][mt] = (wm * 32 + mt * 16 + l15) * 64 + (((kk * 4 + quad) ^ (l15 & 7)) << 3);
            boff[kk][mt] = (wn * 32 + mt * 16 + l15) * 64 + (((kk * 4 + quad) ^ (l15 & 7)) << 3);
        }

    f32x4 acc[2][2];
#pragma unroll
    for (int mt = 0; mt < 2; ++mt)
#pragma unroll
        for (int nt = 0; nt < 2; ++nt)
#pragma unroll
            for (int r = 0; r < 4; ++r) acc[mt][nt][r] = 0.f;

    for (int k0 = 0; k0 < Kd; k0 += 64) {
        __syncthreads();
#pragma unroll
        for (int it = 0; it < 2; ++it) {
            load_lds16(ga + (size_t)it * 32 * Kd + k0, &As[lbase + it * 2048]);
            load_lds16(gb + (size_t)it * 32 * Kd + k0, &Bs[lbase + it * 2048]);
        }
        __syncthreads();

#pragma unroll
        for (int kk = 0; kk < 2; ++kk) {
            bf16x8 af[2], bf[2];
#pragma unroll
            for (int mt = 0; mt < 2; ++mt) af[mt] = *(const bf16x8*)&As[aoff[kk][mt]];
#pragma unroll
            for (int nt = 0; nt < 2; ++nt) bf[nt] = *(const bf16x8*)&Bs[boff[kk][nt]];
#pragma unroll
            for (int mt = 0; mt < 2; ++mt)
#pragma unroll
                for (int nt = 0; nt < 2; ++nt)
                    acc[mt][nt] = __builtin_amdgcn_mfma_f32_16x16x32_bf16(af[mt], bf[nt], acc[mt][nt], 0, 0, 0);
        }
    }

#pragma unroll
    for (int mt = 0; mt < 2; ++mt)
#pragma unroll
        for (int r = 0; r < 4; ++r) {
            int row = bM + wm * 32 + mt * 16 + quad * 4 + r;
            int col = bN + wn * 32 + l15;
            if (OUTF32) {
                float* cp = (float*)Cout + (size_t)row * N + col;
#pragma unroll
                for (int nt = 0; nt < 2; ++nt) cp[nt * 16] = acc[mt][nt][r];
            } else {
                unsigned short* cp = (unsigned short*)Cout + (size_t)row * N + col;
#pragma unroll
                for (int nt = 0; nt < 2; ++nt) cp[nt * 16] = f2bf(acc[mt][nt][r]);
            }
        }
}

// ---------------------------------------------------------------------------
// Flash attention v6b (r11 EXACT — best known): 64q x 32kv per wave, S^T
// trick, __expf, wave-private P, epilogue merge, XCD-aware grid.
// ---------------------------------------------------------------------------
__global__ __launch_bounds__(THREADS, 2)
void attn_mfma6(const unsigned short* __restrict__ Q, const unsigned short* __restrict__ K,
                const unsigned short* __restrict__ Vt, unsigned short* __restrict__ AO) {
    extern __shared__ __align__(16) unsigned short sm[];
    unsigned short* Ks = sm;              // [128kv][64d] swizzled, 8192 shorts
    unsigned short* Vs = sm + 8192;       // [64d][128kv] swizzled, 8192 shorts
    unsigned short* Ps = sm + 16384;      // 4 waves x [64q][40], 10240 shorts
    float* OS = (float*)sm;               // epilogue: 3 x [64d][68q] f32
    float* Lw = (float*)(sm + 26624);     // 256 f32

    const int bid  = blockIdx.x;          // 0..511
    const int slot = bid >> 3;
    const int qq   = slot & 15;
    const int hh   = (bid & 7) + 8 * (slot >> 4);
    const int q0 = qq * 64;
    const int h  = hh & 15;
    const int b  = hh >> 4;

    const int t    = threadIdx.x;
    const int w    = t >> 6;              // kv-quarter owner
    const int lane = t & 63;
    const int l15  = lane & 15;
    const int quad = lane >> 4;

    const unsigned short* Qh = Q + (size_t)b * 1048576 + (size_t)h * 65536 + (size_t)q0 * 64;
    const unsigned short* Kh = K + (size_t)b * 4194304 + (size_t)h * 262144;
    const unsigned short* Vh = Vt + (size_t)(b * 16 + h) * 262144;

    bf16x8 Qb[4][2];
#pragma unroll
    for (int qt = 0; qt < 4; ++qt)
#pragma unroll
        for (int kk = 0; kk < 2; ++kk)
            Qb[qt][kk] = *(const bf16x8*)(Qh + (size_t)(qt * 16 + l15) * 64 + kk * 32 + quad * 8);

    const unsigned short* gK = Kh + (size_t)(t >> 3) * 64 + (((t & 7) ^ ((t >> 3) & 7)) << 3);
    const unsigned short* gV = Vh + (size_t)(t >> 4) * 4096 + (((t & 15) ^ ((t >> 4) & 7)) << 3);
    const int lb = w * 512;

    int koff[2][2];
#pragma unroll
    for (int kvt = 0; kvt < 2; ++kvt)
#pragma unroll
        for (int kk = 0; kk < 2; ++kk)
            koff[kvt][kk] = (w * 32 + kvt * 16 + l15) * 64 + (((kk * 4 + quad) ^ (l15 & 7)) << 3);
    int voff[4];
#pragma unroll
    for (int dt = 0; dt < 4; ++dt)
        voff[dt] = (dt * 16 + l15) * 128 + (((w * 4 + quad) ^ (l15 & 7)) << 3);

    const int pw  = w * 2560;
    const int pq  = pw + l15 * 40;

    f32x4 Oacc[4][4];
#pragma unroll
    for (int qt = 0; qt < 4; ++qt)
#pragma unroll
        for (int dt = 0; dt < 4; ++dt)
#pragma unroll
            for (int r = 0; r < 4; ++r) Oacc[qt][dt][r] = 0.f;
    float lsum[4] = {0.f, 0.f, 0.f, 0.f};

    const float scale = 1.0f / 64.0f;

    for (int kc = 0; kc < 32; ++kc) {
        __syncthreads();
#pragma unroll
        for (int it = 0; it < 4; ++it)
            load_lds16(gK + (size_t)kc * 8192 + it * 2048, &Ks[lb + it * 2048]);
#pragma unroll
        for (int it = 0; it < 4; ++it)
            load_lds16(gV + (size_t)kc * 128 + (size_t)it * 65536, &Vs[lb + it * 2048]);
        __syncthreads();

#pragma unroll
        for (int kvt = 0; kvt < 2; ++kvt) {
            bf16x8 ka = *(const bf16x8*)&Ks[koff[kvt][0]];
            bf16x8 kb = *(const bf16x8*)&Ks[koff[kvt][1]];
#pragma unroll
            for (int qt = 0; qt < 4; ++qt) {
                f32x4 S = {0.f, 0.f, 0.f, 0.f};
                S = __builtin_amdgcn_mfma_f32_16x16x32_bf16(ka, Qb[qt][0], S, 0, 0, 0);
                S = __builtin_amdgcn_mfma_f32_16x16x32_bf16(kb, Qb[qt][1], S, 0, 0, 0);
                float p0 = __expf(S[0] * scale);
                float p1 = __expf(S[1] * scale);
                float p2 = __expf(S[2] * scale);
                float p3 = __expf(S[3] * scale);
                lsum[qt] += (p0 + p1) + (p2 + p3);
                ushort4 pk4;
                pk4.x = f2bf(p0); pk4.y = f2bf(p1); pk4.z = f2bf(p2); pk4.w = f2bf(p3);
                *(ushort4*)&Ps[pq + qt * 640 + kvt * 16 + quad * 4] = pk4;
            }
        }
        asm volatile("s_waitcnt lgkmcnt(0)" ::: "memory");

        bf16x8 Vf[4];
#pragma unroll
        for (int dt = 0; dt < 4; ++dt) Vf[dt] = *(const bf16x8*)&Vs[voff[dt]];
#pragma unroll
        for (int qt = 0; qt < 4; ++qt) {
            bf16x8 Pa = *(const bf16x8*)&Ps[pq + qt * 640 + quad * 8];
#pragma unroll
            for (int dt = 0; dt < 4; ++dt)
                Oacc[qt][dt] = __builtin_amdgcn_mfma_f32_16x16x32_bf16(Pa, Vf[dt], Oacc[qt][dt], 0, 0, 0);
        }
    }

#pragma unroll
    for (int qt = 0; qt < 4; ++qt) {
        float v = lsum[qt];
        v += __shfl_xor(v, 16);
        v += __shfl_xor(v, 32);
        lsum[qt] = v;
    }
    __syncthreads();
    if (lane < 16) {
#pragma unroll
        for (int qt = 0; qt < 4; ++qt)
            Lw[w * 64 + qt * 16 + lane] = lsum[qt];
    }
    if (w > 0) {
        float* myOS = OS + (w - 1) * 4352;
#pragma unroll
        for (int qt = 0; qt < 4; ++qt)
#pragma unroll
            for (int dt = 0; dt < 4; ++dt)
                *(f32x4*)&myOS[(dt * 16 + l15) * 68 + qt * 16 + quad * 4] = Oacc[qt][dt];
    }
    __syncthreads();
    if (w == 0) {
#pragma unroll
        for (int qt = 0; qt < 4; ++qt) {
            f32x4 lv = *(const f32x4*)&Lw[qt * 16 + quad * 4];
            lv += *(const f32x4*)&Lw[64 + qt * 16 + quad * 4];
            lv += *(const f32x4*)&Lw[128 + qt * 16 + quad * 4];
            lv += *(const f32x4*)&Lw[192 + qt * 16 + quad * 4];
            f32x4 inv;
#pragma unroll
            for (int r = 0; r < 4; ++r) inv[r] = 1.0f / lv[r];
#pragma unroll
            for (int dt = 0; dt < 4; ++dt) {
                f32x4 o = Oacc[qt][dt];
                int os = (dt * 16 + l15) * 68 + qt * 16 + quad * 4;
                o += *(const f32x4*)&OS[os];
                o += *(const f32x4*)&OS[4352 + os];
                o += *(const f32x4*)&OS[8704 + os];
#pragma unroll
                for (int r = 0; r < 4; ++r) {
                    int q = qt * 16 + quad * 4 + r;
                    AO[(size_t)b * 1048576 + (size_t)(q0 + q) * 1024 + (h << 6) + dt * 16 + l15]
                        = f2bf(o[r] * inv[r]);
                }
            }
        }
    }
}

// ---------------------------------------------------------------------------
extern "C" void kernel_launch(void* const* d_in, const int* in_sizes, int n_in,
                              void* d_out, int out_size, void* d_ws, size_t ws_size,
                              hipStream_t stream) {
    const float* x_q  = (const float*)d_in[0];  // (2,1024,1024)
    const float* x_kv = (const float*)d_in[1];  // (2,4096,768)
    const float* Wq   = (const float*)d_in[2];
    const float* Wk   = (const float*)d_in[3];
    const float* Wv   = (const float*)d_in[4];
    const float* Wo   = (const float*)d_in[5];
    float* out = (float*)d_out;

    unsigned short* base   = (unsigned short*)d_ws;
    unsigned short* xq_bf  = base;                  // 2097152
    unsigned short* xkv_bf = base + 2097152;        // 6291456
    unsigned short* wq_bf  = base + 8388608;        // 1048576
    unsigned short* wk_bf  = base + 9437184;        //  786432  \ contiguous
    unsigned short* wv_bf  = base + 10223616;       //  786432  / [2048][768]
    unsigned short* wo_bf  = base + 11010048;       // 1048576
    unsigned short* Qw     = base + 12058624;       // 2097152
    unsigned short* Kw     = base + 14155776;       // 8388608
    unsigned short* AOb    = base + 22544384;       // 2097152
    unsigned short* Vtw    = base + 30932992;       // 8388608

    dim3 blk(THREADS);
    cast_inputs<<<dim3(11776), blk, 0, stream>>>(x_q, x_kv, Wq, Wk, Wv, Wo,
                                                 xq_bf, xkv_bf, wq_bf, wk_bf, wv_bf, wo_bf);
    gemm_proj<<<dim3(1536), blk, 0, stream>>>(xkv_bf, wk_bf, Kw, Vtw, xq_bf, wq_bf, Qw);
    attn_mfma6<<<dim3(512), blk, 54272, stream>>>(Qw, Kw, Vtw, AOb);
    gemm_bf16_nt64<true><<<dim3(16, 32), blk, 0, stream>>>(AOb, wo_bf, (void*)out, 2048, 1024, 1024);
}